// Round 16
// baseline (105.737 us; speedup 1.0000x reference)
//
#include <hip/hip_runtime.h>
#include <hip/hip_bf16.h>

#define NEG_SLOPE_C 0.1f
#define LOG2E_C 1.4426950408889634f
#define NEGB_C (-1.3e16f)            // -9e15 * log2(e), rounded down (log2-domain mask value)

constexpr int B_ = 2, N_ = 4096, IN_ = 64, H_ = 4, D_ = 32;

typedef float f32x16 __attribute__((ext_vector_type(16)));
typedef __bf16 bf16x8 __attribute__((ext_vector_type(8)));

__device__ inline unsigned short f2bfu(float x) {           // RNE f32 -> bf16 bits
    unsigned u = __float_as_uint(x);
    return (unsigned short)((u + 0x7fffu + ((u >> 16) & 1u)) >> 16);
}
__device__ inline float bfu2f(unsigned short s) { return __uint_as_float(((unsigned)s) << 16); }
__device__ inline bf16x8 ld_bf8(const unsigned short* p) {
    uint4 r = *reinterpret_cast<const uint4*>(p);
    return __builtin_bit_cast(bf16x8, r);
}

// -------- Kernel P: transpose fc_w [128][64] -> fc_wT [64][128] (32 KB, trivial) --------
__global__ __launch_bounds__(256) void prep_fcT(const float* __restrict__ fc_w,
                                                float* __restrict__ fc_wT) {
    int t = blockIdx.x * 256 + threadIdx.x;   // 8192 threads
    int c = t >> 6, k = t & 63;
    fc_wT[k * 128 + c] = fc_w[c * 64 + k];
}

// ---------- Kernel A: adj -> transposed bitmask maskT[qg*N + m], bit q = adj[qg*32+q][m] ----------
__global__ __launch_bounds__(256) void pack_adjT(const float* __restrict__ adj,
                                                 unsigned* __restrict__ maskT) {
    const int g = blockIdx.x * 4 + (threadIdx.x >> 6);   // global wave id, 8192 total
    const int lane = threadIdx.x & 63;
    const int qg = g >> 6;            // 0..127
    const int mc = g & 63;            // 64-key chunk
    const float* ap = adj + (size_t)qg * 32 * N_ + mc * 64 + lane;
    unsigned word = 0;
    #pragma unroll
    for (int i = 0; i < 32; ++i) {
        unsigned long long ball = __ballot(ap[(size_t)i * N_] != 0.0f);
        word |= (unsigned)((ball >> lane) & 1ULL) << i;
    }
    maskT[(size_t)qg * N_ + mc * 64 + lane] = word;
}

// ------------- Kernel B: projections -> bf16 hi/lo splits + V row-major (bf16) -------------
// 8 rows per block: amortizes block setup, keeps fc_wT hot in L1.
__global__ __launch_bounds__(128) void proj_kernel(
    const float* __restrict__ x, const float* __restrict__ fc_wT,
    const float* __restrict__ fc_b, const float* __restrict__ Q1,
    const float* __restrict__ Q2, const float* __restrict__ K,
    const float* __restrict__ V,
    unsigned short* __restrict__ QtH, unsigned short* __restrict__ QtL,
    unsigned short* __restrict__ KtH, unsigned short* __restrict__ KtL,
    unsigned short* __restrict__ Vt) {
    const int t = threadIdx.x;          // 0..127
    const int h = t >> 5, e = t & 31;
    const float* q1p = Q1 + h * D_ * D_;
    const float* q2p = Q2 + h * D_ * D_;
    const float* kp  = K  + h * D_ * D_;
    const float* vp  = V  + h * D_ * D_;
    __shared__ float xr[IN_];
    __shared__ float xp[H_ * D_];
    const float bias = fc_b[t];
    for (int rr = 0; rr < 8; ++rr) {
        const int bn = blockIdx.x * 8 + rr;   // 0..B*N-1
        const int b = bn / N_, n = bn % N_;
        if (t < IN_) xr[t] = x[(long long)bn * IN_ + t];
        __syncthreads();
        float acc = bias;
        #pragma unroll
        for (int k = 0; k < IN_; ++k) acc += xr[k] * fc_wT[k * 128 + t];  // coalesced, L1-hit
        xp[t] = acc;
        __syncthreads();
        const float* xph = xp + h * D_;
        float a1 = 0.f, a2 = 0.f, ak = 0.f, av = 0.f;
        #pragma unroll
        for (int d = 0; d < D_; ++d) {
            float xv = xph[d];
            a1 += xv * q1p[d * D_ + e];
            a2 += xv * q2p[d * D_ + e];
            ak += xv * kp [d * D_ + e];
            av += xv * vp [d * D_ + e];
        }
        float q = a1 + a2;
        q = q >= 0.f ? q : NEG_SLOPE_C * q;   // Qt = leaky(Qt1+Qt2)
        size_t o = ((size_t)(b * H_ + h) * N_ + n) * D_ + e;
        unsigned short qh = f2bfu(q);
        QtH[o] = qh;
        QtL[o] = f2bfu(q - bfu2f(qh));
        unsigned short kh = f2bfu(ak);
        KtH[o] = kh;
        KtL[o] = f2bfu(ak - bfu2f(kh));
        Vt[o]  = f2bfu(av);                   // row-major, coalesced
        __syncthreads();
    }
}

// ------------- Kernel B2: Vt [bh][n][d] -> VtT [bh][d][n] (LDS tile transpose) -------------
__global__ __launch_bounds__(256) void vtrans(const unsigned short* __restrict__ Vt,
                                              unsigned short* __restrict__ VtT) {
    const int bh = blockIdx.x >> 6;
    const int n0 = (blockIdx.x & 63) * 64;
    __shared__ unsigned short tile[64][34];
    const int t = threadIdx.x;
    {
        const int r = t >> 2, c = (t & 3) * 8;
        uint4 v = *reinterpret_cast<const uint4*>(Vt + ((size_t)bh * N_ + n0 + r) * D_ + c);
        *reinterpret_cast<uint4*>(&tile[r][c]) = v;
    }
    __syncthreads();
    {
        const int d = t >> 3, nc = (t & 7) * 8;
        unsigned short tmp[8];
        #pragma unroll
        for (int j = 0; j < 8; ++j) tmp[j] = tile[nc + j][d];
        *reinterpret_cast<uint4*>(VtT + ((size_t)bh * D_ + d) * N_ + n0 + nc) =
            *reinterpret_cast<uint4*>(tmp);
    }
}

// ---------------- Kernel C: MFMA flash attention, 32 queries/block, 8-way key split ----------------
// r15 main loop verbatim; ONLY change: epilogue merge split over two d-halves reusing a
// half-size LDS buffer (35.8 KB -> 18.5 KB/block) to test whether LDS caps residency at
// 2 blocks/CU (occupancy 51%).
__global__ __launch_bounds__(512, 6) void flash_mfma(
    const unsigned short* __restrict__ QtH, const unsigned short* __restrict__ QtL,
    const unsigned short* __restrict__ KtH, const unsigned short* __restrict__ KtL,
    const unsigned short* __restrict__ VtT, const unsigned* __restrict__ maskT,
    float* __restrict__ out) {
    const int bid = blockIdx.x;      // 1024 blocks
    const int bh = bid >> 7;         // 0..7
    const int qg = bid & 127;        // 32-query group
    const int b = bh >> 2, h = bh & 3;
    const int t = threadIdx.x;
    const int w = t >> 6;            // key-split wave 0..7
    const int wu = __builtin_amdgcn_readfirstlane(w);
    const int l = t & 63;
    const int lq = l & 31;           // this lane's query column
    const int hi = l >> 5;
    const int q0 = qg * 32;

    const size_t bhND = (size_t)bh * N_ * D_;
    // Q B-fragments: B[k=dim][col=q]
    const unsigned short* qbh = QtH + bhND + (size_t)(q0 + lq) * D_ + hi * 8;
    const unsigned short* qbl = QtL + bhND + (size_t)(q0 + lq) * D_ + hi * 8;
    const bf16x8 qh0 = ld_bf8(qbh), qh1 = ld_bf8(qbh + 16);
    const bf16x8 ql0 = ld_bf8(qbl), ql1 = ld_bf8(qbl + 16);

    f32x16 acc = {};                 // O^T: row=d, col=q
    float m_run = -3.0e38f, l_run = 0.f;   // m in log2 units
    const float negb = NEGB_C;
    const float C1 = 0.55f * LOG2E_C, C2 = 0.45f * LOG2E_C;

    const int kw0 = wu * 512;
    const unsigned short* kh_p = KtH + bhND + (size_t)(kw0 + lq) * D_ + hi * 8;
    const unsigned short* kl_p = KtL + bhND + (size_t)(kw0 + lq) * D_ + hi * 8;
    const unsigned short* v_p  = VtT + ((size_t)bh * D_ + lq) * N_ + kw0 + hi * 8;
    const unsigned* mp = maskT + (size_t)qg * N_ + wu * 512;   // wave-uniform

    for (int tt = 0; tt < 16; ++tt) {
        // wave-uniform mask words for this 32-key tile
        unsigned mwd[32];
        {
            const uint4* mq = reinterpret_cast<const uint4*>(mp + tt * 32);
            #pragma unroll
            for (int i = 0; i < 8; ++i) {
                uint4 v = mq[i];
                mwd[i*4] = v.x; mwd[i*4+1] = v.y; mwd[i*4+2] = v.z; mwd[i*4+3] = v.w;
            }
        }
        const bf16x8 kh0v = ld_bf8(kh_p), kh1v = ld_bf8(kh_p + 16);
        const bf16x8 kl0v = ld_bf8(kl_p), kl1v = ld_bf8(kl_p + 16);
        const bf16x8 v0   = ld_bf8(v_p),  v1   = ld_bf8(v_p + 16);
        kh_p += 32 * D_; kl_p += 32 * D_; v_p += 32;

        f32x16 s = {};
        s = __builtin_amdgcn_mfma_f32_32x32x16_bf16(kh0v, qh0, s, 0, 0, 0);
        s = __builtin_amdgcn_mfma_f32_32x32x16_bf16(kh1v, qh1, s, 0, 0, 0);
        s = __builtin_amdgcn_mfma_f32_32x32x16_bf16(kh0v, ql0, s, 0, 0, 0);
        s = __builtin_amdgcn_mfma_f32_32x32x16_bf16(kh1v, ql1, s, 0, 0, 0);
        s = __builtin_amdgcn_mfma_f32_32x32x16_bf16(kl0v, qh0, s, 0, 0, 0);
        s = __builtin_amdgcn_mfma_f32_32x32x16_bf16(kl1v, qh1, s, 0, 0, 0);

        // am = log2-scaled leaky score, masked: 2 fma + 1 cndmask per element
        float am[16];
        #pragma unroll
        for (int r = 0; r < 16; ++r) {
            const int j0 = (r & 3) + 8 * (r >> 2);
            const unsigned long long msk =
                (unsigned long long)mwd[j0] | ((unsigned long long)mwd[j0 + 4] << 32);
            const float v = s[r];
            const float a = fmaf(C2, fabsf(v), C1 * v);
            asm("v_cndmask_b32 %0, %1, %2, %3"
                : "=v"(am[r]) : "v"(negb), "v"(a), "s"(msk));
        }
        // row max (max3-friendly trees), cross-half via shfl_xor (proven path)
        const float x0 = fmaxf(fmaxf(am[0], am[1]), am[2]);
        const float x1 = fmaxf(fmaxf(am[3], am[4]), am[5]);
        const float x2 = fmaxf(fmaxf(am[6], am[7]), am[8]);
        const float x3 = fmaxf(fmaxf(am[9], am[10]), am[11]);
        const float x4 = fmaxf(fmaxf(am[12], am[13]), am[14]);
        const float y0 = fmaxf(fmaxf(x0, x1), x2);
        const float y1 = fmaxf(fmaxf(x3, x4), am[15]);
        float cmax = fmaxf(y0, y1);
        cmax = fmaxf(cmax, __shfl_xor(cmax, 32));
        if (!__all(cmax <= m_run)) {
            const float nm = fmaxf(m_run, cmax);
            const float sc = __builtin_amdgcn_exp2f(m_run - nm);
            l_run *= sc;
            #pragma unroll
            for (int r = 0; r < 16; ++r) acc[r] *= sc;
            m_run = nm;
        }
        float e[16];
        #pragma unroll
        for (int r = 0; r < 16; ++r) e[r] = __builtin_amdgcn_exp2f(am[r] - m_run);
        const float s0 = (e[0] + e[1]) + (e[2] + e[3]);
        const float s1 = (e[4] + e[5]) + (e[6] + e[7]);
        const float s2 = (e[8] + e[9]) + (e[10] + e[11]);
        const float s3 = (e[12] + e[13]) + (e[14] + e[15]);
        float lsum = (s0 + s1) + (s2 + s3);
        lsum += __shfl_xor(lsum, 32);
        l_run += lsum;
        // P -> bf16 pairs: 8 cvt_pk + 4 permlane32_swap (separate asm stmts; proven r3/r5/r7)
        unsigned c0w, c1w, c2w, c3w, c4w, c5w, c6w, c7w;
        asm("v_cvt_pk_bf16_f32 %0, %1, %2" : "=v"(c0w) : "v"(e[0]),  "v"(e[1]));
        asm("v_cvt_pk_bf16_f32 %0, %1, %2" : "=v"(c1w) : "v"(e[2]),  "v"(e[3]));
        asm("v_cvt_pk_bf16_f32 %0, %1, %2" : "=v"(c2w) : "v"(e[4]),  "v"(e[5]));
        asm("v_cvt_pk_bf16_f32 %0, %1, %2" : "=v"(c3w) : "v"(e[6]),  "v"(e[7]));
        asm("v_cvt_pk_bf16_f32 %0, %1, %2" : "=v"(c4w) : "v"(e[8]),  "v"(e[9]));
        asm("v_cvt_pk_bf16_f32 %0, %1, %2" : "=v"(c5w) : "v"(e[10]), "v"(e[11]));
        asm("v_cvt_pk_bf16_f32 %0, %1, %2" : "=v"(c6w) : "v"(e[12]), "v"(e[13]));
        asm("v_cvt_pk_bf16_f32 %0, %1, %2" : "=v"(c7w) : "v"(e[14]), "v"(e[15]));
        asm("v_permlane32_swap_b32 %0, %1" : "+v"(c0w), "+v"(c2w));
        asm("v_permlane32_swap_b32 %0, %1" : "+v"(c1w), "+v"(c3w));
        asm("v_permlane32_swap_b32 %0, %1" : "+v"(c4w), "+v"(c6w));
        asm("v_permlane32_swap_b32 %0, %1" : "+v"(c5w), "+v"(c7w));
        const uint4 b0u = make_uint4(c0w, c1w, c2w, c3w);
        const uint4 b1u = make_uint4(c4w, c5w, c6w, c7w);
        acc = __builtin_amdgcn_mfma_f32_32x32x16_bf16(v0, __builtin_bit_cast(bf16x8, b0u), acc, 0, 0, 0);
        acc = __builtin_amdgcn_mfma_f32_32x32x16_bf16(v1, __builtin_bit_cast(bf16x8, b1u), acc, 0, 0, 0);
    }

    // ---- cross-wave flash merge (8 key-split partials), two d-half passes over half LDS ----
    __shared__ float o_lds[8][16][33];   // 16.9 KB (was [8][32][33] = 33.8 KB)
    __shared__ float m_l[8][32];
    __shared__ float l_l[8][32];
    if (hi == 0) { m_l[w][lq] = m_run; l_l[w][lq] = l_run; }
    // pass 1: d in [0,16)  -> acc regs r<8 (d = (r&3) + 8*(r>>2) + 4*hi, r>>2 in {0,1})
    #pragma unroll
    for (int r = 0; r < 8; ++r) {
        const int d = (r & 3) + 8 * (r >> 2) + 4 * hi;
        o_lds[w][d][lq] = acc[r];
    }
    __syncthreads();
    {
        const int q = t >> 4;        // 0..31
        const int dp = t & 15;       // d = dp
        float M = m_l[0][q];
        #pragma unroll
        for (int w2 = 1; w2 < 8; ++w2) M = fmaxf(M, m_l[w2][q]);
        float L = 0.f, fac[8];
        #pragma unroll
        for (int w2 = 0; w2 < 8; ++w2) {
            fac[w2] = __builtin_amdgcn_exp2f(m_l[w2][q] - M);
            L += l_l[w2][q] * fac[w2];
        }
        const float invL = 1.f / L;
        float o0 = 0.f;
        #pragma unroll
        for (int w2 = 0; w2 < 8; ++w2) o0 += o_lds[w2][dp][q] * fac[w2];
        out[((size_t)(b * N_ + q0 + q) * H_ + h) * D_ + dp] = fmaxf(o0 * invL, 0.f);
    }
    __syncthreads();                 // pass-1 reads complete before overwrite
    // pass 2: d in [16,32) -> acc regs r>=8
    #pragma unroll
    for (int r = 8; r < 16; ++r) {
        const int d = (r & 3) + 8 * (r >> 2) + 4 * hi - 16;
        o_lds[w][d][lq] = acc[r];
    }
    __syncthreads();
    {
        const int q = t >> 4;
        const int dp = t & 15;       // d = 16 + dp
        float M = m_l[0][q];
        #pragma unroll
        for (int w2 = 1; w2 < 8; ++w2) M = fmaxf(M, m_l[w2][q]);
        float L = 0.f, fac[8];
        #pragma unroll
        for (int w2 = 0; w2 < 8; ++w2) {
            fac[w2] = __builtin_amdgcn_exp2f(m_l[w2][q] - M);
            L += l_l[w2][q] * fac[w2];
        }
        const float invL = 1.f / L;
        float o1 = 0.f;
        #pragma unroll
        for (int w2 = 0; w2 < 8; ++w2) o1 += o_lds[w2][dp][q] * fac[w2];
        out[((size_t)(b * N_ + q0 + q) * H_ + h) * D_ + 16 + dp] = fmaxf(o1 * invL, 0.f);
    }
}

extern "C" void kernel_launch(void* const* d_in, const int* in_sizes, int n_in,
                              void* d_out, int out_size, void* d_ws, size_t ws_size,
                              hipStream_t stream) {
    // inputs: vt, x, adj, fc_w, fc_b, Q1, Q2, K, V (all fp32)
    const float* x    = (const float*)d_in[1];
    const float* adj  = (const float*)d_in[2];
    const float* fc_w = (const float*)d_in[3];
    const float* fc_b = (const float*)d_in[4];
    const float* Q1   = (const float*)d_in[5];
    const float* Q2   = (const float*)d_in[6];
    const float* K    = (const float*)d_in[7];
    const float* V    = (const float*)d_in[8];
    float* out = (float*)d_out;

    char* ws = (char*)d_ws;
    const size_t MB = 1024 * 1024;
    unsigned short* QtH = (unsigned short*)(ws);             // 2 MB each
    unsigned short* QtL = (unsigned short*)(ws + 2 * MB);
    unsigned short* KtH = (unsigned short*)(ws + 4 * MB);
    unsigned short* KtL = (unsigned short*)(ws + 6 * MB);
    unsigned short* Vt  = (unsigned short*)(ws + 8 * MB);
    unsigned short* VtT = (unsigned short*)(ws + 10 * MB);
    unsigned*     maskT = (unsigned*)    (ws + 12 * MB);     // 2 MB
    float*        fc_wT = (float*)       (ws + 14 * MB);     // 32 KB

    hipLaunchKernelGGL(prep_fcT, dim3(32), dim3(256), 0, stream, fc_w, fc_wT);
    hipLaunchKernelGGL(pack_adjT, dim3(2048), dim3(256), 0, stream, adj, maskT);
    hipLaunchKernelGGL(proj_kernel, dim3(B_ * N_ / 8), dim3(128), 0, stream,
                       x, fc_wT, fc_b, Q1, Q2, K, V, QtH, QtL, KtH, KtL, Vt);
    hipLaunchKernelGGL(vtrans, dim3(8 * (N_ / 64)), dim3(256), 0, stream, Vt, VtT);
    hipLaunchKernelGGL(flash_mfma, dim3(B_ * H_ * (N_ / 32)), dim3(512), 0, stream,
                       QtH, QtL, KtH, KtL, VtT, maskT, out);
}

// Round 17
// 105.640 us; speedup vs baseline: 1.0009x; 1.0009x over previous
//
#include <hip/hip_runtime.h>
#include <hip/hip_bf16.h>

#define NEG_SLOPE_C 0.1f
#define LOG2E_C 1.4426950408889634f
#define NEGB_C (-1.3e16f)            // -9e15 * log2(e), rounded down (log2-domain mask value)

constexpr int B_ = 2, N_ = 4096, IN_ = 64, H_ = 4, D_ = 32;

typedef float f32x16 __attribute__((ext_vector_type(16)));
typedef __bf16 bf16x8 __attribute__((ext_vector_type(8)));

__device__ inline unsigned short f2bfu(float x) {           // RNE f32 -> bf16 bits
    unsigned u = __float_as_uint(x);
    return (unsigned short)((u + 0x7fffu + ((u >> 16) & 1u)) >> 16);
}
__device__ inline float bfu2f(unsigned short s) { return __uint_as_float(((unsigned)s) << 16); }
__device__ inline bf16x8 ld_bf8(const unsigned short* p) {
    uint4 r = *reinterpret_cast<const uint4*>(p);
    return __builtin_bit_cast(bf16x8, r);
}

// -------- Kernel P: transpose fc_w [128][64] -> fc_wT [64][128] (32 KB, trivial) --------
__global__ __launch_bounds__(256) void prep_fcT(const float* __restrict__ fc_w,
                                                float* __restrict__ fc_wT) {
    int t = blockIdx.x * 256 + threadIdx.x;   // 8192 threads
    int c = t >> 6, k = t & 63;
    fc_wT[k * 128 + c] = fc_w[c * 64 + k];
}

// ---------- Kernel A: adj -> transposed bitmask maskT[qg*N + m], bit q = adj[qg*32+q][m] ----------
__global__ __launch_bounds__(256) void pack_adjT(const float* __restrict__ adj,
                                                 unsigned* __restrict__ maskT) {
    const int g = blockIdx.x * 4 + (threadIdx.x >> 6);   // global wave id, 8192 total
    const int lane = threadIdx.x & 63;
    const int qg = g >> 6;            // 0..127
    const int mc = g & 63;            // 64-key chunk
    const float* ap = adj + (size_t)qg * 32 * N_ + mc * 64 + lane;
    unsigned word = 0;
    #pragma unroll
    for (int i = 0; i < 32; ++i) {
        unsigned long long ball = __ballot(ap[(size_t)i * N_] != 0.0f);
        word |= (unsigned)((ball >> lane) & 1ULL) << i;
    }
    maskT[(size_t)qg * N_ + mc * 64 + lane] = word;
}

// ------------- Kernel B: projections -> bf16 hi/lo splits + V row-major (bf16) -------------
// 8 rows per block: amortizes block setup, keeps fc_wT hot in L1.
__global__ __launch_bounds__(128) void proj_kernel(
    const float* __restrict__ x, const float* __restrict__ fc_wT,
    const float* __restrict__ fc_b, const float* __restrict__ Q1,
    const float* __restrict__ Q2, const float* __restrict__ K,
    const float* __restrict__ V,
    unsigned short* __restrict__ QtH, unsigned short* __restrict__ QtL,
    unsigned short* __restrict__ KtH, unsigned short* __restrict__ KtL,
    unsigned short* __restrict__ Vt) {
    const int t = threadIdx.x;          // 0..127
    const int h = t >> 5, e = t & 31;
    const float* q1p = Q1 + h * D_ * D_;
    const float* q2p = Q2 + h * D_ * D_;
    const float* kp  = K  + h * D_ * D_;
    const float* vp  = V  + h * D_ * D_;
    __shared__ float xr[IN_];
    __shared__ float xp[H_ * D_];
    const float bias = fc_b[t];
    for (int rr = 0; rr < 8; ++rr) {
        const int bn = blockIdx.x * 8 + rr;   // 0..B*N-1
        const int b = bn / N_, n = bn % N_;
        if (t < IN_) xr[t] = x[(long long)bn * IN_ + t];
        __syncthreads();
        float acc = bias;
        #pragma unroll
        for (int k = 0; k < IN_; ++k) acc += xr[k] * fc_wT[k * 128 + t];  // coalesced, L1-hit
        xp[t] = acc;
        __syncthreads();
        const float* xph = xp + h * D_;
        float a1 = 0.f, a2 = 0.f, ak = 0.f, av = 0.f;
        #pragma unroll
        for (int d = 0; d < D_; ++d) {
            float xv = xph[d];
            a1 += xv * q1p[d * D_ + e];
            a2 += xv * q2p[d * D_ + e];
            ak += xv * kp [d * D_ + e];
            av += xv * vp [d * D_ + e];
        }
        float q = a1 + a2;
        q = q >= 0.f ? q : NEG_SLOPE_C * q;   // Qt = leaky(Qt1+Qt2)
        size_t o = ((size_t)(b * H_ + h) * N_ + n) * D_ + e;
        unsigned short qh = f2bfu(q);
        QtH[o] = qh;
        QtL[o] = f2bfu(q - bfu2f(qh));
        unsigned short kh = f2bfu(ak);
        KtH[o] = kh;
        KtL[o] = f2bfu(ak - bfu2f(kh));
        Vt[o]  = f2bfu(av);                   // row-major, coalesced
        __syncthreads();
    }
}

// ------------- Kernel B2: Vt [bh][n][d] -> VtT [bh][d][n] (LDS tile transpose) -------------
__global__ __launch_bounds__(256) void vtrans(const unsigned short* __restrict__ Vt,
                                              unsigned short* __restrict__ VtT) {
    const int bh = blockIdx.x >> 6;
    const int n0 = (blockIdx.x & 63) * 64;
    __shared__ unsigned short tile[64][34];
    const int t = threadIdx.x;
    {
        const int r = t >> 2, c = (t & 3) * 8;
        uint4 v = *reinterpret_cast<const uint4*>(Vt + ((size_t)bh * N_ + n0 + r) * D_ + c);
        *reinterpret_cast<uint4*>(&tile[r][c]) = v;
    }
    __syncthreads();
    {
        const int d = t >> 3, nc = (t & 7) * 8;
        unsigned short tmp[8];
        #pragma unroll
        for (int j = 0; j < 8; ++j) tmp[j] = tile[nc + j][d];
        *reinterpret_cast<uint4*>(VtT + ((size_t)bh * D_ + d) * N_ + n0 + nc) =
            *reinterpret_cast<uint4*>(tmp);
    }
}

// ---------------- Kernel C: MFMA flash attention, 32 queries/block, 8-way key split ----------------
__global__ __launch_bounds__(512, 6) void flash_mfma(
    const unsigned short* __restrict__ QtH, const unsigned short* __restrict__ QtL,
    const unsigned short* __restrict__ KtH, const unsigned short* __restrict__ KtL,
    const unsigned short* __restrict__ VtT, const unsigned* __restrict__ maskT,
    float* __restrict__ out) {
    const int bid = blockIdx.x;      // 1024 blocks
    const int bh = bid >> 7;         // 0..7
    const int qg = bid & 127;        // 32-query group
    const int b = bh >> 2, h = bh & 3;
    const int t = threadIdx.x;
    const int w = t >> 6;            // key-split wave 0..7
    const int wu = __builtin_amdgcn_readfirstlane(w);
    const int l = t & 63;
    const int lq = l & 31;           // this lane's query column
    const int hi = l >> 5;
    const int q0 = qg * 32;

    const size_t bhND = (size_t)bh * N_ * D_;
    // Q B-fragments: B[k=dim][col=q]
    const unsigned short* qbh = QtH + bhND + (size_t)(q0 + lq) * D_ + hi * 8;
    const unsigned short* qbl = QtL + bhND + (size_t)(q0 + lq) * D_ + hi * 8;
    const bf16x8 qh0 = ld_bf8(qbh), qh1 = ld_bf8(qbh + 16);
    const bf16x8 ql0 = ld_bf8(qbl), ql1 = ld_bf8(qbl + 16);

    f32x16 acc = {};                 // O^T: row=d, col=q
    float m_run = -3.0e38f, l_run = 0.f;   // m in log2 units
    const float negb = NEGB_C;
    const float C1 = 0.55f * LOG2E_C, C2 = 0.45f * LOG2E_C;

    const int kw0 = wu * 512;
    const unsigned short* kh_p = KtH + bhND + (size_t)(kw0 + lq) * D_ + hi * 8;
    const unsigned short* kl_p = KtL + bhND + (size_t)(kw0 + lq) * D_ + hi * 8;
    const unsigned short* v_p  = VtT + ((size_t)bh * D_ + lq) * N_ + kw0 + hi * 8;
    const unsigned* mp = maskT + (size_t)qg * N_ + wu * 512;   // wave-uniform

    for (int tt = 0; tt < 16; ++tt) {
        // wave-uniform mask words for this 32-key tile
        unsigned mwd[32];
        {
            const uint4* mq = reinterpret_cast<const uint4*>(mp + tt * 32);
            #pragma unroll
            for (int i = 0; i < 8; ++i) {
                uint4 v = mq[i];
                mwd[i*4] = v.x; mwd[i*4+1] = v.y; mwd[i*4+2] = v.z; mwd[i*4+3] = v.w;
            }
        }
        const bf16x8 kh0v = ld_bf8(kh_p), kh1v = ld_bf8(kh_p + 16);
        const bf16x8 kl0v = ld_bf8(kl_p), kl1v = ld_bf8(kl_p + 16);
        const bf16x8 v0   = ld_bf8(v_p),  v1   = ld_bf8(v_p + 16);
        kh_p += 32 * D_; kl_p += 32 * D_; v_p += 32;

        f32x16 s = {};
        s = __builtin_amdgcn_mfma_f32_32x32x16_bf16(kh0v, qh0, s, 0, 0, 0);
        s = __builtin_amdgcn_mfma_f32_32x32x16_bf16(kh1v, qh1, s, 0, 0, 0);
        s = __builtin_amdgcn_mfma_f32_32x32x16_bf16(kh0v, ql0, s, 0, 0, 0);
        s = __builtin_amdgcn_mfma_f32_32x32x16_bf16(kh1v, ql1, s, 0, 0, 0);
        s = __builtin_amdgcn_mfma_f32_32x32x16_bf16(kl0v, qh0, s, 0, 0, 0);
        s = __builtin_amdgcn_mfma_f32_32x32x16_bf16(kl1v, qh1, s, 0, 0, 0);

        // am = log2-scaled leaky score, masked: 2 fma + 1 cndmask per element
        float am[16];
        #pragma unroll
        for (int r = 0; r < 16; ++r) {
            const int j0 = (r & 3) + 8 * (r >> 2);
            const unsigned long long msk =
                (unsigned long long)mwd[j0] | ((unsigned long long)mwd[j0 + 4] << 32);
            const float v = s[r];
            const float a = fmaf(C2, fabsf(v), C1 * v);
            asm("v_cndmask_b32 %0, %1, %2, %3"
                : "=v"(am[r]) : "v"(negb), "v"(a), "s"(msk));
        }
        // row max (max3-friendly trees), cross-half via shfl_xor (proven path)
        const float x0 = fmaxf(fmaxf(am[0], am[1]), am[2]);
        const float x1 = fmaxf(fmaxf(am[3], am[4]), am[5]);
        const float x2 = fmaxf(fmaxf(am[6], am[7]), am[8]);
        const float x3 = fmaxf(fmaxf(am[9], am[10]), am[11]);
        const float x4 = fmaxf(fmaxf(am[12], am[13]), am[14]);
        const float y0 = fmaxf(fmaxf(x0, x1), x2);
        const float y1 = fmaxf(fmaxf(x3, x4), am[15]);
        float cmax = fmaxf(y0, y1);
        cmax = fmaxf(cmax, __shfl_xor(cmax, 32));
        if (!__all(cmax <= m_run)) {
            const float nm = fmaxf(m_run, cmax);
            const float sc = __builtin_amdgcn_exp2f(m_run - nm);
            l_run *= sc;
            #pragma unroll
            for (int r = 0; r < 16; ++r) acc[r] *= sc;
            m_run = nm;
        }
        float e[16];
        #pragma unroll
        for (int r = 0; r < 16; ++r) e[r] = __builtin_amdgcn_exp2f(am[r] - m_run);
        const float s0 = (e[0] + e[1]) + (e[2] + e[3]);
        const float s1 = (e[4] + e[5]) + (e[6] + e[7]);
        const float s2 = (e[8] + e[9]) + (e[10] + e[11]);
        const float s3 = (e[12] + e[13]) + (e[14] + e[15]);
        float lsum = (s0 + s1) + (s2 + s3);
        lsum += __shfl_xor(lsum, 32);
        l_run += lsum;
        // P -> bf16 pairs: 8 cvt_pk + 4 permlane32_swap (separate asm stmts; proven r3/r5/r7)
        unsigned c0w, c1w, c2w, c3w, c4w, c5w, c6w, c7w;
        asm("v_cvt_pk_bf16_f32 %0, %1, %2" : "=v"(c0w) : "v"(e[0]),  "v"(e[1]));
        asm("v_cvt_pk_bf16_f32 %0, %1, %2" : "=v"(c1w) : "v"(e[2]),  "v"(e[3]));
        asm("v_cvt_pk_bf16_f32 %0, %1, %2" : "=v"(c2w) : "v"(e[4]),  "v"(e[5]));
        asm("v_cvt_pk_bf16_f32 %0, %1, %2" : "=v"(c3w) : "v"(e[6]),  "v"(e[7]));
        asm("v_cvt_pk_bf16_f32 %0, %1, %2" : "=v"(c4w) : "v"(e[8]),  "v"(e[9]));
        asm("v_cvt_pk_bf16_f32 %0, %1, %2" : "=v"(c5w) : "v"(e[10]), "v"(e[11]));
        asm("v_cvt_pk_bf16_f32 %0, %1, %2" : "=v"(c6w) : "v"(e[12]), "v"(e[13]));
        asm("v_cvt_pk_bf16_f32 %0, %1, %2" : "=v"(c7w) : "v"(e[14]), "v"(e[15]));
        asm("v_permlane32_swap_b32 %0, %1" : "+v"(c0w), "+v"(c2w));
        asm("v_permlane32_swap_b32 %0, %1" : "+v"(c1w), "+v"(c3w));
        asm("v_permlane32_swap_b32 %0, %1" : "+v"(c4w), "+v"(c6w));
        asm("v_permlane32_swap_b32 %0, %1" : "+v"(c5w), "+v"(c7w));
        const uint4 b0u = make_uint4(c0w, c1w, c2w, c3w);
        const uint4 b1u = make_uint4(c4w, c5w, c6w, c7w);
        acc = __builtin_amdgcn_mfma_f32_32x32x16_bf16(v0, __builtin_bit_cast(bf16x8, b0u), acc, 0, 0, 0);
        acc = __builtin_amdgcn_mfma_f32_32x32x16_bf16(v1, __builtin_bit_cast(bf16x8, b1u), acc, 0, 0, 0);
    }

    // ---- cross-wave flash merge (8 key-split partials) ----
    __shared__ float o_lds[8][32][33];
    __shared__ float m_l[8][32];
    __shared__ float l_l[8][32];
    if (hi == 0) { m_l[w][lq] = m_run; l_l[w][lq] = l_run; }
    #pragma unroll
    for (int r = 0; r < 16; ++r) {
        const int d = (r & 3) + 8 * (r >> 2) + 4 * hi;
        o_lds[w][d][lq] = acc[r];
    }
    __syncthreads();
    {
        const int q = t >> 4;        // 0..31
        const int dp = t & 15;       // float2 over d
        float M = m_l[0][q];
        #pragma unroll
        for (int w2 = 1; w2 < 8; ++w2) M = fmaxf(M, m_l[w2][q]);
        float L = 0.f, fac[8];
        #pragma unroll
        for (int w2 = 0; w2 < 8; ++w2) {
            fac[w2] = __builtin_amdgcn_exp2f(m_l[w2][q] - M);
            L += l_l[w2][q] * fac[w2];
        }
        const float invL = 1.f / L;
        float o0 = 0.f, o1 = 0.f;
        #pragma unroll
        for (int w2 = 0; w2 < 8; ++w2) {
            o0 += o_lds[w2][dp * 2][q] * fac[w2];
            o1 += o_lds[w2][dp * 2 + 1][q] * fac[w2];
        }
        o0 = fmaxf(o0 * invL, 0.f);
        o1 = fmaxf(o1 * invL, 0.f);
        float2 ov = make_float2(o0, o1);
        *reinterpret_cast<float2*>(out + ((size_t)(b * N_ + q0 + q) * H_ + h) * D_ + dp * 2) = ov;
    }
}

extern "C" void kernel_launch(void* const* d_in, const int* in_sizes, int n_in,
                              void* d_out, int out_size, void* d_ws, size_t ws_size,
                              hipStream_t stream) {
    // inputs: vt, x, adj, fc_w, fc_b, Q1, Q2, K, V (all fp32)
    const float* x    = (const float*)d_in[1];
    const float* adj  = (const float*)d_in[2];
    const float* fc_w = (const float*)d_in[3];
    const float* fc_b = (const float*)d_in[4];
    const float* Q1   = (const float*)d_in[5];
    const float* Q2   = (const float*)d_in[6];
    const float* K    = (const float*)d_in[7];
    const float* V    = (const float*)d_in[8];
    float* out = (float*)d_out;

    char* ws = (char*)d_ws;
    const size_t MB = 1024 * 1024;
    unsigned short* QtH = (unsigned short*)(ws);             // 2 MB each
    unsigned short* QtL = (unsigned short*)(ws + 2 * MB);
    unsigned short* KtH = (unsigned short*)(ws + 4 * MB);
    unsigned short* KtL = (unsigned short*)(ws + 6 * MB);
    unsigned short* Vt  = (unsigned short*)(ws + 8 * MB);
    unsigned short* VtT = (unsigned short*)(ws + 10 * MB);
    unsigned*     maskT = (unsigned*)    (ws + 12 * MB);     // 2 MB
    float*        fc_wT = (float*)       (ws + 14 * MB);     // 32 KB

    hipLaunchKernelGGL(prep_fcT, dim3(32), dim3(256), 0, stream, fc_w, fc_wT);
    hipLaunchKernelGGL(pack_adjT, dim3(2048), dim3(256), 0, stream, adj, maskT);
    hipLaunchKernelGGL(proj_kernel, dim3(B_ * N_ / 8), dim3(128), 0, stream,
                       x, fc_wT, fc_b, Q1, Q2, K, V, QtH, QtL, KtH, KtL, Vt);
    hipLaunchKernelGGL(vtrans, dim3(8 * (N_ / 64)), dim3(256), 0, stream, Vt, VtT);
    hipLaunchKernelGGL(flash_mfma, dim3(B_ * H_ * (N_ / 32)), dim3(512), 0, stream,
                       QtH, QtL, KtH, KtL, VtT, maskT, out);
}

// Round 18
// 104.834 us; speedup vs baseline: 1.0086x; 1.0077x over previous
//
#include <hip/hip_runtime.h>
#include <hip/hip_bf16.h>

#define NEG_SLOPE_C 0.1f
#define LOG2E_C 1.4426950408889634f
#define NEGB_C (-1.3e16f)            // -9e15 * log2(e), rounded down (log2-domain mask value)
#define DEFER_THR 8.0f               // T13 defer-max: skip rescale unless max grew by >8 log2-units

constexpr int B_ = 2, N_ = 4096, IN_ = 64, H_ = 4, D_ = 32;

typedef float f32x16 __attribute__((ext_vector_type(16)));
typedef __bf16 bf16x8 __attribute__((ext_vector_type(8)));

__device__ inline unsigned short f2bfu(float x) {           // RNE f32 -> bf16 bits
    unsigned u = __float_as_uint(x);
    return (unsigned short)((u + 0x7fffu + ((u >> 16) & 1u)) >> 16);
}
__device__ inline float bfu2f(unsigned short s) { return __uint_as_float(((unsigned)s) << 16); }
__device__ inline bf16x8 ld_bf8(const unsigned short* p) {
    uint4 r = *reinterpret_cast<const uint4*>(p);
    return __builtin_bit_cast(bf16x8, r);
}

// -------- Kernel P: transpose fc_w [128][64] -> fc_wT [64][128] (32 KB, trivial) --------
__global__ __launch_bounds__(256) void prep_fcT(const float* __restrict__ fc_w,
                                                float* __restrict__ fc_wT) {
    int t = blockIdx.x * 256 + threadIdx.x;   // 8192 threads
    int c = t >> 6, k = t & 63;
    fc_wT[k * 128 + c] = fc_w[c * 64 + k];
}

// ---------- Kernel A: adj -> transposed bitmask maskT[qg*N + m], bit q = adj[qg*32+q][m] ----------
__global__ __launch_bounds__(256) void pack_adjT(const float* __restrict__ adj,
                                                 unsigned* __restrict__ maskT) {
    const int g = blockIdx.x * 4 + (threadIdx.x >> 6);   // global wave id, 8192 total
    const int lane = threadIdx.x & 63;
    const int qg = g >> 6;            // 0..127
    const int mc = g & 63;            // 64-key chunk
    const float* ap = adj + (size_t)qg * 32 * N_ + mc * 64 + lane;
    unsigned word = 0;
    #pragma unroll
    for (int i = 0; i < 32; ++i) {
        unsigned long long ball = __ballot(ap[(size_t)i * N_] != 0.0f);
        word |= (unsigned)((ball >> lane) & 1ULL) << i;
    }
    maskT[(size_t)qg * N_ + mc * 64 + lane] = word;
}

// ------------- Kernel B: projections -> bf16 hi/lo splits + V row-major (bf16) -------------
// 8 rows per block: amortizes block setup, keeps fc_wT hot in L1.
__global__ __launch_bounds__(128) void proj_kernel(
    const float* __restrict__ x, const float* __restrict__ fc_wT,
    const float* __restrict__ fc_b, const float* __restrict__ Q1,
    const float* __restrict__ Q2, const float* __restrict__ K,
    const float* __restrict__ V,
    unsigned short* __restrict__ QtH, unsigned short* __restrict__ QtL,
    unsigned short* __restrict__ KtH, unsigned short* __restrict__ KtL,
    unsigned short* __restrict__ Vt) {
    const int t = threadIdx.x;          // 0..127
    const int h = t >> 5, e = t & 31;
    const float* q1p = Q1 + h * D_ * D_;
    const float* q2p = Q2 + h * D_ * D_;
    const float* kp  = K  + h * D_ * D_;
    const float* vp  = V  + h * D_ * D_;
    __shared__ float xr[IN_];
    __shared__ float xp[H_ * D_];
    const float bias = fc_b[t];
    for (int rr = 0; rr < 8; ++rr) {
        const int bn = blockIdx.x * 8 + rr;   // 0..B*N-1
        const int b = bn / N_, n = bn % N_;
        if (t < IN_) xr[t] = x[(long long)bn * IN_ + t];
        __syncthreads();
        float acc = bias;
        #pragma unroll
        for (int k = 0; k < IN_; ++k) acc += xr[k] * fc_wT[k * 128 + t];  // coalesced, L1-hit
        xp[t] = acc;
        __syncthreads();
        const float* xph = xp + h * D_;
        float a1 = 0.f, a2 = 0.f, ak = 0.f, av = 0.f;
        #pragma unroll
        for (int d = 0; d < D_; ++d) {
            float xv = xph[d];
            a1 += xv * q1p[d * D_ + e];
            a2 += xv * q2p[d * D_ + e];
            ak += xv * kp [d * D_ + e];
            av += xv * vp [d * D_ + e];
        }
        float q = a1 + a2;
        q = q >= 0.f ? q : NEG_SLOPE_C * q;   // Qt = leaky(Qt1+Qt2)
        size_t o = ((size_t)(b * H_ + h) * N_ + n) * D_ + e;
        unsigned short qh = f2bfu(q);
        QtH[o] = qh;
        QtL[o] = f2bfu(q - bfu2f(qh));
        unsigned short kh = f2bfu(ak);
        KtH[o] = kh;
        KtL[o] = f2bfu(ak - bfu2f(kh));
        Vt[o]  = f2bfu(av);                   // row-major, coalesced
        __syncthreads();
    }
}

// ------------- Kernel B2: Vt [bh][n][d] -> VtT [bh][d][n] (LDS tile transpose) -------------
__global__ __launch_bounds__(256) void vtrans(const unsigned short* __restrict__ Vt,
                                              unsigned short* __restrict__ VtT) {
    const int bh = blockIdx.x >> 6;
    const int n0 = (blockIdx.x & 63) * 64;
    __shared__ unsigned short tile[64][34];
    const int t = threadIdx.x;
    {
        const int r = t >> 2, c = (t & 3) * 8;
        uint4 v = *reinterpret_cast<const uint4*>(Vt + ((size_t)bh * N_ + n0 + r) * D_ + c);
        *reinterpret_cast<uint4*>(&tile[r][c]) = v;
    }
    __syncthreads();
    {
        const int d = t >> 3, nc = (t & 7) * 8;
        unsigned short tmp[8];
        #pragma unroll
        for (int j = 0; j < 8; ++j) tmp[j] = tile[nc + j][d];
        *reinterpret_cast<uint4*>(VtT + ((size_t)bh * D_ + d) * N_ + n0 + nc) =
            *reinterpret_cast<uint4*>(tmp);
    }
}

// ---------------- Kernel C: MFMA flash attention, 32 queries/block, 8-way key split ----------------
// r15 champion; ONLY change: defer-max threshold (T13) on the rescale guard -> rescale body
// (16 acc-muls + exp on the serial chain) runs ~2-4/16 tiles instead of ~16/16.
__global__ __launch_bounds__(512, 6) void flash_mfma(
    const unsigned short* __restrict__ QtH, const unsigned short* __restrict__ QtL,
    const unsigned short* __restrict__ KtH, const unsigned short* __restrict__ KtL,
    const unsigned short* __restrict__ VtT, const unsigned* __restrict__ maskT,
    float* __restrict__ out) {
    const int bid = blockIdx.x;      // 1024 blocks
    const int bh = bid >> 7;         // 0..7
    const int qg = bid & 127;        // 32-query group
    const int b = bh >> 2, h = bh & 3;
    const int t = threadIdx.x;
    const int w = t >> 6;            // key-split wave 0..7
    const int wu = __builtin_amdgcn_readfirstlane(w);
    const int l = t & 63;
    const int lq = l & 31;           // this lane's query column
    const int hi = l >> 5;
    const int q0 = qg * 32;

    const size_t bhND = (size_t)bh * N_ * D_;
    // Q B-fragments: B[k=dim][col=q]
    const unsigned short* qbh = QtH + bhND + (size_t)(q0 + lq) * D_ + hi * 8;
    const unsigned short* qbl = QtL + bhND + (size_t)(q0 + lq) * D_ + hi * 8;
    const bf16x8 qh0 = ld_bf8(qbh), qh1 = ld_bf8(qbh + 16);
    const bf16x8 ql0 = ld_bf8(qbl), ql1 = ld_bf8(qbl + 16);

    f32x16 acc = {};                 // O^T: row=d, col=q
    float m_run = -3.0e38f, l_run = 0.f;   // m in log2 units
    const float negb = NEGB_C;
    const float C1 = 0.55f * LOG2E_C, C2 = 0.45f * LOG2E_C;

    const int kw0 = wu * 512;
    const unsigned short* kh_p = KtH + bhND + (size_t)(kw0 + lq) * D_ + hi * 8;
    const unsigned short* kl_p = KtL + bhND + (size_t)(kw0 + lq) * D_ + hi * 8;
    const unsigned short* v_p  = VtT + ((size_t)bh * D_ + lq) * N_ + kw0 + hi * 8;
    const unsigned* mp = maskT + (size_t)qg * N_ + wu * 512;   // wave-uniform

    for (int tt = 0; tt < 16; ++tt) {
        // wave-uniform mask words for this 32-key tile
        unsigned mwd[32];
        {
            const uint4* mq = reinterpret_cast<const uint4*>(mp + tt * 32);
            #pragma unroll
            for (int i = 0; i < 8; ++i) {
                uint4 v = mq[i];
                mwd[i*4] = v.x; mwd[i*4+1] = v.y; mwd[i*4+2] = v.z; mwd[i*4+3] = v.w;
            }
        }
        const bf16x8 kh0v = ld_bf8(kh_p), kh1v = ld_bf8(kh_p + 16);
        const bf16x8 kl0v = ld_bf8(kl_p), kl1v = ld_bf8(kl_p + 16);
        const bf16x8 v0   = ld_bf8(v_p),  v1   = ld_bf8(v_p + 16);
        kh_p += 32 * D_; kl_p += 32 * D_; v_p += 32;

        f32x16 s = {};
        s = __builtin_amdgcn_mfma_f32_32x32x16_bf16(kh0v, qh0, s, 0, 0, 0);
        s = __builtin_amdgcn_mfma_f32_32x32x16_bf16(kh1v, qh1, s, 0, 0, 0);
        s = __builtin_amdgcn_mfma_f32_32x32x16_bf16(kh0v, ql0, s, 0, 0, 0);
        s = __builtin_amdgcn_mfma_f32_32x32x16_bf16(kh1v, ql1, s, 0, 0, 0);
        s = __builtin_amdgcn_mfma_f32_32x32x16_bf16(kl0v, qh0, s, 0, 0, 0);
        s = __builtin_amdgcn_mfma_f32_32x32x16_bf16(kl1v, qh1, s, 0, 0, 0);

        // am = log2-scaled leaky score, masked: 2 fma + 1 cndmask per element
        float am[16];
        #pragma unroll
        for (int r = 0; r < 16; ++r) {
            const int j0 = (r & 3) + 8 * (r >> 2);
            const unsigned long long msk =
                (unsigned long long)mwd[j0] | ((unsigned long long)mwd[j0 + 4] << 32);
            const float v = s[r];
            const float a = fmaf(C2, fabsf(v), C1 * v);
            asm("v_cndmask_b32 %0, %1, %2, %3"
                : "=v"(am[r]) : "v"(negb), "v"(a), "s"(msk));
        }
        // row max (max3-friendly trees), cross-half via shfl_xor (proven path)
        const float x0 = fmaxf(fmaxf(am[0], am[1]), am[2]);
        const float x1 = fmaxf(fmaxf(am[3], am[4]), am[5]);
        const float x2 = fmaxf(fmaxf(am[6], am[7]), am[8]);
        const float x3 = fmaxf(fmaxf(am[9], am[10]), am[11]);
        const float x4 = fmaxf(fmaxf(am[12], am[13]), am[14]);
        const float y0 = fmaxf(fmaxf(x0, x1), x2);
        const float y1 = fmaxf(fmaxf(x3, x4), am[15]);
        float cmax = fmaxf(y0, y1);
        cmax = fmaxf(cmax, __shfl_xor(cmax, 32));
        // T13 defer-max: only rescale when the max grew by >8 log2-units.
        // Skipped case: e = exp2(am - m_run) <= 2^8 = 256 (bf16/f32 safe); merge math is
        // reference-point invariant (m_l/l_l/o_lds all use the same m_run).
        if (!__all(cmax <= m_run + DEFER_THR)) {
            const float nm = fmaxf(m_run, cmax);
            const float sc = __builtin_amdgcn_exp2f(m_run - nm);
            l_run *= sc;
            #pragma unroll
            for (int r = 0; r < 16; ++r) acc[r] *= sc;
            m_run = nm;
        }
        float e[16];
        #pragma unroll
        for (int r = 0; r < 16; ++r) e[r] = __builtin_amdgcn_exp2f(am[r] - m_run);
        const float s0 = (e[0] + e[1]) + (e[2] + e[3]);
        const float s1 = (e[4] + e[5]) + (e[6] + e[7]);
        const float s2 = (e[8] + e[9]) + (e[10] + e[11]);
        const float s3 = (e[12] + e[13]) + (e[14] + e[15]);
        float lsum = (s0 + s1) + (s2 + s3);
        lsum += __shfl_xor(lsum, 32);
        l_run += lsum;
        // P -> bf16 pairs: 8 cvt_pk + 4 permlane32_swap (separate asm stmts; proven r3/r5/r7)
        unsigned c0w, c1w, c2w, c3w, c4w, c5w, c6w, c7w;
        asm("v_cvt_pk_bf16_f32 %0, %1, %2" : "=v"(c0w) : "v"(e[0]),  "v"(e[1]));
        asm("v_cvt_pk_bf16_f32 %0, %1, %2" : "=v"(c1w) : "v"(e[2]),  "v"(e[3]));
        asm("v_cvt_pk_bf16_f32 %0, %1, %2" : "=v"(c2w) : "v"(e[4]),  "v"(e[5]));
        asm("v_cvt_pk_bf16_f32 %0, %1, %2" : "=v"(c3w) : "v"(e[6]),  "v"(e[7]));
        asm("v_cvt_pk_bf16_f32 %0, %1, %2" : "=v"(c4w) : "v"(e[8]),  "v"(e[9]));
        asm("v_cvt_pk_bf16_f32 %0, %1, %2" : "=v"(c5w) : "v"(e[10]), "v"(e[11]));
        asm("v_cvt_pk_bf16_f32 %0, %1, %2" : "=v"(c6w) : "v"(e[12]), "v"(e[13]));
        asm("v_cvt_pk_bf16_f32 %0, %1, %2" : "=v"(c7w) : "v"(e[14]), "v"(e[15]));
        asm("v_permlane32_swap_b32 %0, %1" : "+v"(c0w), "+v"(c2w));
        asm("v_permlane32_swap_b32 %0, %1" : "+v"(c1w), "+v"(c3w));
        asm("v_permlane32_swap_b32 %0, %1" : "+v"(c4w), "+v"(c6w));
        asm("v_permlane32_swap_b32 %0, %1" : "+v"(c5w), "+v"(c7w));
        const uint4 b0u = make_uint4(c0w, c1w, c2w, c3w);
        const uint4 b1u = make_uint4(c4w, c5w, c6w, c7w);
        acc = __builtin_amdgcn_mfma_f32_32x32x16_bf16(v0, __builtin_bit_cast(bf16x8, b0u), acc, 0, 0, 0);
        acc = __builtin_amdgcn_mfma_f32_32x32x16_bf16(v1, __builtin_bit_cast(bf16x8, b1u), acc, 0, 0, 0);
    }

    // ---- cross-wave flash merge (8 key-split partials) ----
    __shared__ float o_lds[8][32][33];
    __shared__ float m_l[8][32];
    __shared__ float l_l[8][32];
    if (hi == 0) { m_l[w][lq] = m_run; l_l[w][lq] = l_run; }
    #pragma unroll
    for (int r = 0; r < 16; ++r) {
        const int d = (r & 3) + 8 * (r >> 2) + 4 * hi;
        o_lds[w][d][lq] = acc[r];
    }
    __syncthreads();
    {
        const int q = t >> 4;        // 0..31
        const int dp = t & 15;       // float2 over d
        float M = m_l[0][q];
        #pragma unroll
        for (int w2 = 1; w2 < 8; ++w2) M = fmaxf(M, m_l[w2][q]);
        float L = 0.f, fac[8];
        #pragma unroll
        for (int w2 = 0; w2 < 8; ++w2) {
            fac[w2] = __builtin_amdgcn_exp2f(m_l[w2][q] - M);
            L += l_l[w2][q] * fac[w2];
        }
        const float invL = 1.f / L;
        float o0 = 0.f, o1 = 0.f;
        #pragma unroll
        for (int w2 = 0; w2 < 8; ++w2) {
            o0 += o_lds[w2][dp * 2][q] * fac[w2];
            o1 += o_lds[w2][dp * 2 + 1][q] * fac[w2];
        }
        o0 = fmaxf(o0 * invL, 0.f);
        o1 = fmaxf(o1 * invL, 0.f);
        float2 ov = make_float2(o0, o1);
        *reinterpret_cast<float2*>(out + ((size_t)(b * N_ + q0 + q) * H_ + h) * D_ + dp * 2) = ov;
    }
}

extern "C" void kernel_launch(void* const* d_in, const int* in_sizes, int n_in,
                              void* d_out, int out_size, void* d_ws, size_t ws_size,
                              hipStream_t stream) {
    // inputs: vt, x, adj, fc_w, fc_b, Q1, Q2, K, V (all fp32)
    const float* x    = (const float*)d_in[1];
    const float* adj  = (const float*)d_in[2];
    const float* fc_w = (const float*)d_in[3];
    const float* fc_b = (const float*)d_in[4];
    const float* Q1   = (const float*)d_in[5];
    const float* Q2   = (const float*)d_in[6];
    const float* K    = (const float*)d_in[7];
    const float* V    = (const float*)d_in[8];
    float* out = (float*)d_out;

    char* ws = (char*)d_ws;
    const size_t MB = 1024 * 1024;
    unsigned short* QtH = (unsigned short*)(ws);             // 2 MB each
    unsigned short* QtL = (unsigned short*)(ws + 2 * MB);
    unsigned short* KtH = (unsigned short*)(ws + 4 * MB);
    unsigned short* KtL = (unsigned short*)(ws + 6 * MB);
    unsigned short* Vt  = (unsigned short*)(ws + 8 * MB);
    unsigned short* VtT = (unsigned short*)(ws + 10 * MB);
    unsigned*     maskT = (unsigned*)    (ws + 12 * MB);     // 2 MB
    float*        fc_wT = (float*)       (ws + 14 * MB);     // 32 KB

    hipLaunchKernelGGL(prep_fcT, dim3(32), dim3(256), 0, stream, fc_w, fc_wT);
    hipLaunchKernelGGL(pack_adjT, dim3(2048), dim3(256), 0, stream, adj, maskT);
    hipLaunchKernelGGL(proj_kernel, dim3(B_ * N_ / 8), dim3(128), 0, stream,
                       x, fc_wT, fc_b, Q1, Q2, K, V, QtH, QtL, KtH, KtL, Vt);
    hipLaunchKernelGGL(vtrans, dim3(8 * (N_ / 64)), dim3(256), 0, stream, Vt, VtT);
    hipLaunchKernelGGL(flash_mfma, dim3(B_ * H_ * (N_ / 32)), dim3(512), 0, stream,
                       QtH, QtL, KtH, KtL, VtT, maskT, out);
}

// Round 19
// 102.881 us; speedup vs baseline: 1.0278x; 1.0190x over previous
//
#include <hip/hip_runtime.h>
#include <hip/hip_bf16.h>

#define NEG_SLOPE_C 0.1f
#define LOG2E_C 1.4426950408889634f
#define NEGB_C (-1.3e16f)            // -9e15 * log2(e), rounded down (log2-domain mask value)
#define DEFER_THR 8.0f               // T13 defer-max: skip rescale unless max grew by >8 log2-units

constexpr int B_ = 2, N_ = 4096, IN_ = 64, H_ = 4, D_ = 32;

typedef float f32x16 __attribute__((ext_vector_type(16)));
typedef __bf16 bf16x8 __attribute__((ext_vector_type(8)));

__device__ inline unsigned short f2bfu(float x) {           // RNE f32 -> bf16 bits
    unsigned u = __float_as_uint(x);
    return (unsigned short)((u + 0x7fffu + ((u >> 16) & 1u)) >> 16);
}
__device__ inline float bfu2f(unsigned short s) { return __uint_as_float(((unsigned)s) << 16); }
__device__ inline bf16x8 ld_bf8(const unsigned short* p) {
    uint4 r = *reinterpret_cast<const uint4*>(p);
    return __builtin_bit_cast(bf16x8, r);
}

// -------- Kernel P: transpose fc_w [128][64] -> fc_wT [64][128] (32 KB, trivial) --------
__global__ __launch_bounds__(256) void prep_fcT(const float* __restrict__ fc_w,
                                                float* __restrict__ fc_wT) {
    int t = blockIdx.x * 256 + threadIdx.x;   // 8192 threads
    int c = t >> 6, k = t & 63;
    fc_wT[k * 128 + c] = fc_w[c * 64 + k];
}

// ---- Fused aux kernel: blocks [0,1024) = proj (verbatim body), [1024,5120) = pack_adjT ----
// proj (compute-bound, ~6us) and pack (BW-bound on 64MB adj, ~11us) are independent; fusing
// them into one launch lets their waves co-reside -> aux time ~= max, not sum.
__global__ __launch_bounds__(128) void fused_proj_pack(
    const float* __restrict__ x, const float* __restrict__ fc_wT,
    const float* __restrict__ fc_b, const float* __restrict__ Q1,
    const float* __restrict__ Q2, const float* __restrict__ K,
    const float* __restrict__ V, const float* __restrict__ adj,
    unsigned short* __restrict__ QtH, unsigned short* __restrict__ QtL,
    unsigned short* __restrict__ KtH, unsigned short* __restrict__ KtL,
    unsigned short* __restrict__ Vt, unsigned* __restrict__ maskT) {
    if (blockIdx.x < 1024) {
        // ---------------- proj body (r18-verbatim): 8 rows per block ----------------
        const int t = threadIdx.x;          // 0..127
        const int h = t >> 5, e = t & 31;
        const float* q1p = Q1 + h * D_ * D_;
        const float* q2p = Q2 + h * D_ * D_;
        const float* kp  = K  + h * D_ * D_;
        const float* vp  = V  + h * D_ * D_;
        __shared__ float xr[IN_];
        __shared__ float xp[H_ * D_];
        const float bias = fc_b[t];
        for (int rr = 0; rr < 8; ++rr) {
            const int bn = blockIdx.x * 8 + rr;   // 0..B*N-1
            const int b = bn / N_, n = bn % N_;
            if (t < IN_) xr[t] = x[(long long)bn * IN_ + t];
            __syncthreads();
            float acc = bias;
            #pragma unroll
            for (int k = 0; k < IN_; ++k) acc += xr[k] * fc_wT[k * 128 + t];  // coalesced, L1-hit
            xp[t] = acc;
            __syncthreads();
            const float* xph = xp + h * D_;
            float a1 = 0.f, a2 = 0.f, ak = 0.f, av = 0.f;
            #pragma unroll
            for (int d = 0; d < D_; ++d) {
                float xv = xph[d];
                a1 += xv * q1p[d * D_ + e];
                a2 += xv * q2p[d * D_ + e];
                ak += xv * kp [d * D_ + e];
                av += xv * vp [d * D_ + e];
            }
            float q = a1 + a2;
            q = q >= 0.f ? q : NEG_SLOPE_C * q;   // Qt = leaky(Qt1+Qt2)
            size_t o = ((size_t)(b * H_ + h) * N_ + n) * D_ + e;
            unsigned short qh = f2bfu(q);
            QtH[o] = qh;
            QtL[o] = f2bfu(q - bfu2f(qh));
            unsigned short kh = f2bfu(ak);
            KtH[o] = kh;
            KtL[o] = f2bfu(ak - bfu2f(kh));
            Vt[o]  = f2bfu(av);                   // row-major, coalesced
            __syncthreads();
        }
    } else {
        // ---------------- pack_adjT body (r18-verbatim math; 2 waves/block) ----------------
        const int pb = blockIdx.x - 1024;            // 0..4095
        const int g = pb * 2 + (threadIdx.x >> 6);   // global wave id, 8192 total (same coverage)
        const int lane = threadIdx.x & 63;
        const int qg = g >> 6;            // 0..127
        const int mc = g & 63;            // 64-key chunk
        const float* ap = adj + (size_t)qg * 32 * N_ + mc * 64 + lane;
        unsigned word = 0;
        #pragma unroll
        for (int i = 0; i < 32; ++i) {
            unsigned long long ball = __ballot(ap[(size_t)i * N_] != 0.0f);
            word |= (unsigned)((ball >> lane) & 1ULL) << i;
        }
        maskT[(size_t)qg * N_ + mc * 64 + lane] = word;
    }
}

// ------------- Kernel B2: Vt [bh][n][d] -> VtT [bh][d][n] (LDS tile transpose) -------------
__global__ __launch_bounds__(256) void vtrans(const unsigned short* __restrict__ Vt,
                                              unsigned short* __restrict__ VtT) {
    const int bh = blockIdx.x >> 6;
    const int n0 = (blockIdx.x & 63) * 64;
    __shared__ unsigned short tile[64][34];
    const int t = threadIdx.x;
    {
        const int r = t >> 2, c = (t & 3) * 8;
        uint4 v = *reinterpret_cast<const uint4*>(Vt + ((size_t)bh * N_ + n0 + r) * D_ + c);
        *reinterpret_cast<uint4*>(&tile[r][c]) = v;
    }
    __syncthreads();
    {
        const int d = t >> 3, nc = (t & 7) * 8;
        unsigned short tmp[8];
        #pragma unroll
        for (int j = 0; j < 8; ++j) tmp[j] = tile[nc + j][d];
        *reinterpret_cast<uint4*>(VtT + ((size_t)bh * D_ + d) * N_ + n0 + nc) =
            *reinterpret_cast<uint4*>(tmp);
    }
}

// ---------------- Kernel C: MFMA flash attention, 32 queries/block, 8-way key split ----------------
// r18 champion verbatim (defer-max kept).
__global__ __launch_bounds__(512, 6) void flash_mfma(
    const unsigned short* __restrict__ QtH, const unsigned short* __restrict__ QtL,
    const unsigned short* __restrict__ KtH, const unsigned short* __restrict__ KtL,
    const unsigned short* __restrict__ VtT, const unsigned* __restrict__ maskT,
    float* __restrict__ out) {
    const int bid = blockIdx.x;      // 1024 blocks
    const int bh = bid >> 7;         // 0..7
    const int qg = bid & 127;        // 32-query group
    const int b = bh >> 2, h = bh & 3;
    const int t = threadIdx.x;
    const int w = t >> 6;            // key-split wave 0..7
    const int wu = __builtin_amdgcn_readfirstlane(w);
    const int l = t & 63;
    const int lq = l & 31;           // this lane's query column
    const int hi = l >> 5;
    const int q0 = qg * 32;

    const size_t bhND = (size_t)bh * N_ * D_;
    // Q B-fragments: B[k=dim][col=q]
    const unsigned short* qbh = QtH + bhND + (size_t)(q0 + lq) * D_ + hi * 8;
    const unsigned short* qbl = QtL + bhND + (size_t)(q0 + lq) * D_ + hi * 8;
    const bf16x8 qh0 = ld_bf8(qbh), qh1 = ld_bf8(qbh + 16);
    const bf16x8 ql0 = ld_bf8(qbl), ql1 = ld_bf8(qbl + 16);

    f32x16 acc = {};                 // O^T: row=d, col=q
    float m_run = -3.0e38f, l_run = 0.f;   // m in log2 units
    const float negb = NEGB_C;
    const float C1 = 0.55f * LOG2E_C, C2 = 0.45f * LOG2E_C;

    const int kw0 = wu * 512;
    const unsigned short* kh_p = KtH + bhND + (size_t)(kw0 + lq) * D_ + hi * 8;
    const unsigned short* kl_p = KtL + bhND + (size_t)(kw0 + lq) * D_ + hi * 8;
    const unsigned short* v_p  = VtT + ((size_t)bh * D_ + lq) * N_ + kw0 + hi * 8;
    const unsigned* mp = maskT + (size_t)qg * N_ + wu * 512;   // wave-uniform

    for (int tt = 0; tt < 16; ++tt) {
        // wave-uniform mask words for this 32-key tile
        unsigned mwd[32];
        {
            const uint4* mq = reinterpret_cast<const uint4*>(mp + tt * 32);
            #pragma unroll
            for (int i = 0; i < 8; ++i) {
                uint4 v = mq[i];
                mwd[i*4] = v.x; mwd[i*4+1] = v.y; mwd[i*4+2] = v.z; mwd[i*4+3] = v.w;
            }
        }
        const bf16x8 kh0v = ld_bf8(kh_p), kh1v = ld_bf8(kh_p + 16);
        const bf16x8 kl0v = ld_bf8(kl_p), kl1v = ld_bf8(kl_p + 16);
        const bf16x8 v0   = ld_bf8(v_p),  v1   = ld_bf8(v_p + 16);
        kh_p += 32 * D_; kl_p += 32 * D_; v_p += 32;

        f32x16 s = {};
        s = __builtin_amdgcn_mfma_f32_32x32x16_bf16(kh0v, qh0, s, 0, 0, 0);
        s = __builtin_amdgcn_mfma_f32_32x32x16_bf16(kh1v, qh1, s, 0, 0, 0);
        s = __builtin_amdgcn_mfma_f32_32x32x16_bf16(kh0v, ql0, s, 0, 0, 0);
        s = __builtin_amdgcn_mfma_f32_32x32x16_bf16(kh1v, ql1, s, 0, 0, 0);
        s = __builtin_amdgcn_mfma_f32_32x32x16_bf16(kl0v, qh0, s, 0, 0, 0);
        s = __builtin_amdgcn_mfma_f32_32x32x16_bf16(kl1v, qh1, s, 0, 0, 0);

        // am = log2-scaled leaky score, masked: 2 fma + 1 cndmask per element
        float am[16];
        #pragma unroll
        for (int r = 0; r < 16; ++r) {
            const int j0 = (r & 3) + 8 * (r >> 2);
            const unsigned long long msk =
                (unsigned long long)mwd[j0] | ((unsigned long long)mwd[j0 + 4] << 32);
            const float v = s[r];
            const float a = fmaf(C2, fabsf(v), C1 * v);
            asm("v_cndmask_b32 %0, %1, %2, %3"
                : "=v"(am[r]) : "v"(negb), "v"(a), "s"(msk));
        }
        // row max (max3-friendly trees), cross-half via shfl_xor (proven path)
        const float x0 = fmaxf(fmaxf(am[0], am[1]), am[2]);
        const float x1 = fmaxf(fmaxf(am[3], am[4]), am[5]);
        const float x2 = fmaxf(fmaxf(am[6], am[7]), am[8]);
        const float x3 = fmaxf(fmaxf(am[9], am[10]), am[11]);
        const float x4 = fmaxf(fmaxf(am[12], am[13]), am[14]);
        const float y0 = fmaxf(fmaxf(x0, x1), x2);
        const float y1 = fmaxf(fmaxf(x3, x4), am[15]);
        float cmax = fmaxf(y0, y1);
        cmax = fmaxf(cmax, __shfl_xor(cmax, 32));
        // T13 defer-max: only rescale when the max grew by >8 log2-units.
        if (!__all(cmax <= m_run + DEFER_THR)) {
            const float nm = fmaxf(m_run, cmax);
            const float sc = __builtin_amdgcn_exp2f(m_run - nm);
            l_run *= sc;
            #pragma unroll
            for (int r = 0; r < 16; ++r) acc[r] *= sc;
            m_run = nm;
        }
        float e[16];
        #pragma unroll
        for (int r = 0; r < 16; ++r) e[r] = __builtin_amdgcn_exp2f(am[r] - m_run);
        const float s0 = (e[0] + e[1]) + (e[2] + e[3]);
        const float s1 = (e[4] + e[5]) + (e[6] + e[7]);
        const float s2 = (e[8] + e[9]) + (e[10] + e[11]);
        const float s3 = (e[12] + e[13]) + (e[14] + e[15]);
        float lsum = (s0 + s1) + (s2 + s3);
        lsum += __shfl_xor(lsum, 32);
        l_run += lsum;
        // P -> bf16 pairs: 8 cvt_pk + 4 permlane32_swap (separate asm stmts; proven r3/r5/r7)
        unsigned c0w, c1w, c2w, c3w, c4w, c5w, c6w, c7w;
        asm("v_cvt_pk_bf16_f32 %0, %1, %2" : "=v"(c0w) : "v"(e[0]),  "v"(e[1]));
        asm("v_cvt_pk_bf16_f32 %0, %1, %2" : "=v"(c1w) : "v"(e[2]),  "v"(e[3]));
        asm("v_cvt_pk_bf16_f32 %0, %1, %2" : "=v"(c2w) : "v"(e[4]),  "v"(e[5]));
        asm("v_cvt_pk_bf16_f32 %0, %1, %2" : "=v"(c3w) : "v"(e[6]),  "v"(e[7]));
        asm("v_cvt_pk_bf16_f32 %0, %1, %2" : "=v"(c4w) : "v"(e[8]),  "v"(e[9]));
        asm("v_cvt_pk_bf16_f32 %0, %1, %2" : "=v"(c5w) : "v"(e[10]), "v"(e[11]));
        asm("v_cvt_pk_bf16_f32 %0, %1, %2" : "=v"(c6w) : "v"(e[12]), "v"(e[13]));
        asm("v_cvt_pk_bf16_f32 %0, %1, %2" : "=v"(c7w) : "v"(e[14]), "v"(e[15]));
        asm("v_permlane32_swap_b32 %0, %1" : "+v"(c0w), "+v"(c2w));
        asm("v_permlane32_swap_b32 %0, %1" : "+v"(c1w), "+v"(c3w));
        asm("v_permlane32_swap_b32 %0, %1" : "+v"(c4w), "+v"(c6w));
        asm("v_permlane32_swap_b32 %0, %1" : "+v"(c5w), "+v"(c7w));
        const uint4 b0u = make_uint4(c0w, c1w, c2w, c3w);
        const uint4 b1u = make_uint4(c4w, c5w, c6w, c7w);
        acc = __builtin_amdgcn_mfma_f32_32x32x16_bf16(v0, __builtin_bit_cast(bf16x8, b0u), acc, 0, 0, 0);
        acc = __builtin_amdgcn_mfma_f32_32x32x16_bf16(v1, __builtin_bit_cast(bf16x8, b1u), acc, 0, 0, 0);
    }

    // ---- cross-wave flash merge (8 key-split partials) ----
    __shared__ float o_lds[8][32][33];
    __shared__ float m_l[8][32];
    __shared__ float l_l[8][32];
    if (hi == 0) { m_l[w][lq] = m_run; l_l[w][lq] = l_run; }
    #pragma unroll
    for (int r = 0; r < 16; ++r) {
        const int d = (r & 3) + 8 * (r >> 2) + 4 * hi;
        o_lds[w][d][lq] = acc[r];
    }
    __syncthreads();
    {
        const int q = t >> 4;        // 0..31
        const int dp = t & 15;       // float2 over d
        float M = m_l[0][q];
        #pragma unroll
        for (int w2 = 1; w2 < 8; ++w2) M = fmaxf(M, m_l[w2][q]);
        float L = 0.f, fac[8];
        #pragma unroll
        for (int w2 = 0; w2 < 8; ++w2) {
            fac[w2] = __builtin_amdgcn_exp2f(m_l[w2][q] - M);
            L += l_l[w2][q] * fac[w2];
        }
        const float invL = 1.f / L;
        float o0 = 0.f, o1 = 0.f;
        #pragma unroll
        for (int w2 = 0; w2 < 8; ++w2) {
            o0 += o_lds[w2][dp * 2][q] * fac[w2];
            o1 += o_lds[w2][dp * 2 + 1][q] * fac[w2];
        }
        o0 = fmaxf(o0 * invL, 0.f);
        o1 = fmaxf(o1 * invL, 0.f);
        float2 ov = make_float2(o0, o1);
        *reinterpret_cast<float2*>(out + ((size_t)(b * N_ + q0 + q) * H_ + h) * D_ + dp * 2) = ov;
    }
}

extern "C" void kernel_launch(void* const* d_in, const int* in_sizes, int n_in,
                              void* d_out, int out_size, void* d_ws, size_t ws_size,
                              hipStream_t stream) {
    // inputs: vt, x, adj, fc_w, fc_b, Q1, Q2, K, V (all fp32)
    const float* x    = (const float*)d_in[1];
    const float* adj  = (const float*)d_in[2];
    const float* fc_w = (const float*)d_in[3];
    const float* fc_b = (const float*)d_in[4];
    const float* Q1   = (const float*)d_in[5];
    const float* Q2   = (const float*)d_in[6];
    const float* K    = (const float*)d_in[7];
    const float* V    = (const float*)d_in[8];
    float* out = (float*)d_out;

    char* ws = (char*)d_ws;
    const size_t MB = 1024 * 1024;
    unsigned short* QtH = (unsigned short*)(ws);             // 2 MB each
    unsigned short* QtL = (unsigned short*)(ws + 2 * MB);
    unsigned short* KtH = (unsigned short*)(ws + 4 * MB);
    unsigned short* KtL = (unsigned short*)(ws + 6 * MB);
    unsigned short* Vt  = (unsigned short*)(ws + 8 * MB);
    unsigned short* VtT = (unsigned short*)(ws + 10 * MB);
    unsigned*     maskT = (unsigned*)    (ws + 12 * MB);     // 2 MB
    float*        fc_wT = (float*)       (ws + 14 * MB);     // 32 KB

    hipLaunchKernelGGL(prep_fcT, dim3(32), dim3(256), 0, stream, fc_w, fc_wT);
    hipLaunchKernelGGL(fused_proj_pack, dim3(1024 + 4096), dim3(128), 0, stream,
                       x, fc_wT, fc_b, Q1, Q2, K, V, adj,
                       QtH, QtL, KtH, KtL, Vt, maskT);
    hipLaunchKernelGGL(vtrans, dim3(8 * (N_ / 64)), dim3(256), 0, stream, Vt, VtT);
    hipLaunchKernelGGL(flash_mfma, dim3(B_ * H_ * (N_ / 32)), dim3(512), 0, stream,
                       QtH, QtL, KtH, KtL, VtT, maskT, out);
}

// Round 20
// 98.931 us; speedup vs baseline: 1.0688x; 1.0399x over previous
//
#include <hip/hip_runtime.h>
#include <hip/hip_bf16.h>

#define NEG_SLOPE_C 0.1f
#define LOG2E_C 1.4426950408889634f
#define NEGB_C (-1.3e16f)            // -9e15 * log2(e), rounded down (log2-domain mask value)
#define DEFER_THR 8.0f               // T13 defer-max: skip rescale unless max grew by >8 log2-units

constexpr int B_ = 2, N_ = 4096, IN_ = 64, H_ = 4, D_ = 32;

typedef float f32x16 __attribute__((ext_vector_type(16)));
typedef __bf16 bf16x8 __attribute__((ext_vector_type(8)));

__device__ inline unsigned short f2bfu(float x) {           // RNE f32 -> bf16 bits
    unsigned u = __float_as_uint(x);
    return (unsigned short)((u + 0x7fffu + ((u >> 16) & 1u)) >> 16);
}
__device__ inline float bfu2f(unsigned short s) { return __uint_as_float(((unsigned)s) << 16); }
__device__ inline bf16x8 ld_bf8(const unsigned short* p) {
    uint4 r = *reinterpret_cast<const uint4*>(p);
    return __builtin_bit_cast(bf16x8, r);
}

// ---- Fused aux kernel: blocks [0,1024) = proj (register-hoisted weights), [1024,5120) = pack_adjT ----
// proj (compute-bound) and pack (BW-bound, 64MB adj) are independent -> co-resident waves, time ~= max.
// prep_fcT eliminated: each proj thread hoists its 64-float fc_w row into registers ONCE per block
// (32KB fc_w is L2-resident; r3's scatter cost was per-row-per-k, this is once). Values and
// accumulation order identical to the fc_wT path -> bit-identical output.
__global__ __launch_bounds__(128) void fused_proj_pack(
    const float* __restrict__ x, const float* __restrict__ fc_w,
    const float* __restrict__ fc_b, const float* __restrict__ Q1,
    const float* __restrict__ Q2, const float* __restrict__ K,
    const float* __restrict__ V, const float* __restrict__ adj,
    unsigned short* __restrict__ QtH, unsigned short* __restrict__ QtL,
    unsigned short* __restrict__ KtH, unsigned short* __restrict__ KtL,
    unsigned short* __restrict__ Vt, unsigned* __restrict__ maskT) {
    if (blockIdx.x < 1024) {
        // ---------------- proj body: 8 rows per block, weights in registers ----------------
        const int t = threadIdx.x;          // 0..127
        const int h = t >> 5, e = t & 31;
        const float* q1p = Q1 + h * D_ * D_;
        const float* q2p = Q2 + h * D_ * D_;
        const float* kp  = K  + h * D_ * D_;
        const float* vp  = V  + h * D_ * D_;
        __shared__ float xr[IN_];
        __shared__ float xp[H_ * D_];
        const float bias = fc_b[t];
        // hoist this output channel's weight row (fc_w[t][0..63]) into registers
        float wreg[IN_];
        {
            const float4* wr4 = reinterpret_cast<const float4*>(fc_w + t * IN_);
            #pragma unroll
            for (int i = 0; i < IN_ / 4; ++i) {
                const float4 v4 = wr4[i];
                wreg[i*4+0] = v4.x; wreg[i*4+1] = v4.y; wreg[i*4+2] = v4.z; wreg[i*4+3] = v4.w;
            }
        }
        for (int rr = 0; rr < 8; ++rr) {
            const int bn = blockIdx.x * 8 + rr;   // 0..B*N-1
            const int b = bn / N_, n = bn % N_;
            if (t < IN_) xr[t] = x[(long long)bn * IN_ + t];
            __syncthreads();
            float acc = bias;
            #pragma unroll
            for (int k = 0; k < IN_; ++k) acc += xr[k] * wreg[k];   // register-resident FMAs
            xp[t] = acc;
            __syncthreads();
            const float* xph = xp + h * D_;
            float a1 = 0.f, a2 = 0.f, ak = 0.f, av = 0.f;
            #pragma unroll
            for (int d = 0; d < D_; ++d) {
                float xv = xph[d];
                a1 += xv * q1p[d * D_ + e];
                a2 += xv * q2p[d * D_ + e];
                ak += xv * kp [d * D_ + e];
                av += xv * vp [d * D_ + e];
            }
            float q = a1 + a2;
            q = q >= 0.f ? q : NEG_SLOPE_C * q;   // Qt = leaky(Qt1+Qt2)
            size_t o = ((size_t)(b * H_ + h) * N_ + n) * D_ + e;
            unsigned short qh = f2bfu(q);
            QtH[o] = qh;
            QtL[o] = f2bfu(q - bfu2f(qh));
            unsigned short kh = f2bfu(ak);
            KtH[o] = kh;
            KtL[o] = f2bfu(ak - bfu2f(kh));
            Vt[o]  = f2bfu(av);                   // row-major, coalesced
            __syncthreads();
        }
    } else {
        // ---------------- pack_adjT body (r19-verbatim; 2 waves/block) ----------------
        const int pb = blockIdx.x - 1024;            // 0..4095
        const int g = pb * 2 + (threadIdx.x >> 6);   // global wave id, 8192 total (same coverage)
        const int lane = threadIdx.x & 63;
        const int qg = g >> 6;            // 0..127
        const int mc = g & 63;            // 64-key chunk
        const float* ap = adj + (size_t)qg * 32 * N_ + mc * 64 + lane;
        unsigned word = 0;
        #pragma unroll
        for (int i = 0; i < 32; ++i) {
            unsigned long long ball = __ballot(ap[(size_t)i * N_] != 0.0f);
            word |= (unsigned)((ball >> lane) & 1ULL) << i;
        }
        maskT[(size_t)qg * N_ + mc * 64 + lane] = word;
    }
}

// ------------- Kernel B2: Vt [bh][n][d] -> VtT [bh][d][n] (LDS tile transpose) -------------
__global__ __launch_bounds__(256) void vtrans(const unsigned short* __restrict__ Vt,
                                              unsigned short* __restrict__ VtT) {
    const int bh = blockIdx.x >> 6;
    const int n0 = (blockIdx.x & 63) * 64;
    __shared__ unsigned short tile[64][34];
    const int t = threadIdx.x;
    {
        const int r = t >> 2, c = (t & 3) * 8;
        uint4 v = *reinterpret_cast<const uint4*>(Vt + ((size_t)bh * N_ + n0 + r) * D_ + c);
        *reinterpret_cast<uint4*>(&tile[r][c]) = v;
    }
    __syncthreads();
    {
        const int d = t >> 3, nc = (t & 7) * 8;
        unsigned short tmp[8];
        #pragma unroll
        for (int j = 0; j < 8; ++j) tmp[j] = tile[nc + j][d];
        *reinterpret_cast<uint4*>(VtT + ((size_t)bh * D_ + d) * N_ + n0 + nc) =
            *reinterpret_cast<uint4*>(tmp);
    }
}

// ---------------- Kernel C: MFMA flash attention, 32 queries/block, 8-way key split ----------------
// r19 champion verbatim (defer-max kept).
__global__ __launch_bounds__(512, 6) void flash_mfma(
    const unsigned short* __restrict__ QtH, const unsigned short* __restrict__ QtL,
    const unsigned short* __restrict__ KtH, const unsigned short* __restrict__ KtL,
    const unsigned short* __restrict__ VtT, const unsigned* __restrict__ maskT,
    float* __restrict__ out) {
    const int bid = blockIdx.x;      // 1024 blocks
    const int bh = bid >> 7;         // 0..7
    const int qg = bid & 127;        // 32-query group
    const int b = bh >> 2, h = bh & 3;
    const int t = threadIdx.x;
    const int w = t >> 6;            // key-split wave 0..7
    const int wu = __builtin_amdgcn_readfirstlane(w);
    const int l = t & 63;
    const int lq = l & 31;           // this lane's query column
    const int hi = l >> 5;
    const int q0 = qg * 32;

    const size_t bhND = (size_t)bh * N_ * D_;
    // Q B-fragments: B[k=dim][col=q]
    const unsigned short* qbh = QtH + bhND + (size_t)(q0 + lq) * D_ + hi * 8;
    const unsigned short* qbl = QtL + bhND + (size_t)(q0 + lq) * D_ + hi * 8;
    const bf16x8 qh0 = ld_bf8(qbh), qh1 = ld_bf8(qbh + 16);
    const bf16x8 ql0 = ld_bf8(qbl), ql1 = ld_bf8(qbl + 16);

    f32x16 acc = {};                 // O^T: row=d, col=q
    float m_run = -3.0e38f, l_run = 0.f;   // m in log2 units
    const float negb = NEGB_C;
    const float C1 = 0.55f * LOG2E_C, C2 = 0.45f * LOG2E_C;

    const int kw0 = wu * 512;
    const unsigned short* kh_p = KtH + bhND + (size_t)(kw0 + lq) * D_ + hi * 8;
    const unsigned short* kl_p = KtL + bhND + (size_t)(kw0 + lq) * D_ + hi * 8;
    const unsigned short* v_p  = VtT + ((size_t)bh * D_ + lq) * N_ + kw0 + hi * 8;
    const unsigned* mp = maskT + (size_t)qg * N_ + wu * 512;   // wave-uniform

    for (int tt = 0; tt < 16; ++tt) {
        // wave-uniform mask words for this 32-key tile
        unsigned mwd[32];
        {
            const uint4* mq = reinterpret_cast<const uint4*>(mp + tt * 32);
            #pragma unroll
            for (int i = 0; i < 8; ++i) {
                uint4 v = mq[i];
                mwd[i*4] = v.x; mwd[i*4+1] = v.y; mwd[i*4+2] = v.z; mwd[i*4+3] = v.w;
            }
        }
        const bf16x8 kh0v = ld_bf8(kh_p), kh1v = ld_bf8(kh_p + 16);
        const bf16x8 kl0v = ld_bf8(kl_p), kl1v = ld_bf8(kl_p + 16);
        const bf16x8 v0   = ld_bf8(v_p),  v1   = ld_bf8(v_p + 16);
        kh_p += 32 * D_; kl_p += 32 * D_; v_p += 32;

        f32x16 s = {};
        s = __builtin_amdgcn_mfma_f32_32x32x16_bf16(kh0v, qh0, s, 0, 0, 0);
        s = __builtin_amdgcn_mfma_f32_32x32x16_bf16(kh1v, qh1, s, 0, 0, 0);
        s = __builtin_amdgcn_mfma_f32_32x32x16_bf16(kh0v, ql0, s, 0, 0, 0);
        s = __builtin_amdgcn_mfma_f32_32x32x16_bf16(kh1v, ql1, s, 0, 0, 0);
        s = __builtin_amdgcn_mfma_f32_32x32x16_bf16(kl0v, qh0, s, 0, 0, 0);
        s = __builtin_amdgcn_mfma_f32_32x32x16_bf16(kl1v, qh1, s, 0, 0, 0);

        // am = log2-scaled leaky score, masked: 2 fma + 1 cndmask per element
        float am[16];
        #pragma unroll
        for (int r = 0; r < 16; ++r) {
            const int j0 = (r & 3) + 8 * (r >> 2);
            const unsigned long long msk =
                (unsigned long long)mwd[j0] | ((unsigned long long)mwd[j0 + 4] << 32);
            const float v = s[r];
            const float a = fmaf(C2, fabsf(v), C1 * v);
            asm("v_cndmask_b32 %0, %1, %2, %3"
                : "=v"(am[r]) : "v"(negb), "v"(a), "s"(msk));
        }
        // row max (max3-friendly trees), cross-half via shfl_xor (proven path)
        const float x0 = fmaxf(fmaxf(am[0], am[1]), am[2]);
        const float x1 = fmaxf(fmaxf(am[3], am[4]), am[5]);
        const float x2 = fmaxf(fmaxf(am[6], am[7]), am[8]);
        const float x3 = fmaxf(fmaxf(am[9], am[10]), am[11]);
        const float x4 = fmaxf(fmaxf(am[12], am[13]), am[14]);
        const float y0 = fmaxf(fmaxf(x0, x1), x2);
        const float y1 = fmaxf(fmaxf(x3, x4), am[15]);
        float cmax = fmaxf(y0, y1);
        cmax = fmaxf(cmax, __shfl_xor(cmax, 32));
        // T13 defer-max: only rescale when the max grew by >8 log2-units.
        if (!__all(cmax <= m_run + DEFER_THR)) {
            const float nm = fmaxf(m_run, cmax);
            const float sc = __builtin_amdgcn_exp2f(m_run - nm);
            l_run *= sc;
            #pragma unroll
            for (int r = 0; r < 16; ++r) acc[r] *= sc;
            m_run = nm;
        }
        float e[16];
        #pragma unroll
        for (int r = 0; r < 16; ++r) e[r] = __builtin_amdgcn_exp2f(am[r] - m_run);
        const float s0 = (e[0] + e[1]) + (e[2] + e[3]);
        const float s1 = (e[4] + e[5]) + (e[6] + e[7]);
        const float s2 = (e[8] + e[9]) + (e[10] + e[11]);
        const float s3 = (e[12] + e[13]) + (e[14] + e[15]);
        float lsum = (s0 + s1) + (s2 + s3);
        lsum += __shfl_xor(lsum, 32);
        l_run += lsum;
        // P -> bf16 pairs: 8 cvt_pk + 4 permlane32_swap (separate asm stmts; proven r3/r5/r7)
        unsigned c0w, c1w, c2w, c3w, c4w, c5w, c6w, c7w;
        asm("v_cvt_pk_bf16_f32 %0, %1, %2" : "=v"(c0w) : "v"(e[0]),  "v"(e[1]));
        asm("v_cvt_pk_bf16_f32 %0, %1, %2" : "=v"(c1w) : "v"(e[2]),  "v"(e[3]));
        asm("v_cvt_pk_bf16_f32 %0, %1, %2" : "=v"(c2w) : "v"(e[4]),  "v"(e[5]));
        asm("v_cvt_pk_bf16_f32 %0, %1, %2" : "=v"(c3w) : "v"(e[6]),  "v"(e[7]));
        asm("v_cvt_pk_bf16_f32 %0, %1, %2" : "=v"(c4w) : "v"(e[8]),  "v"(e[9]));
        asm("v_cvt_pk_bf16_f32 %0, %1, %2" : "=v"(c5w) : "v"(e[10]), "v"(e[11]));
        asm("v_cvt_pk_bf16_f32 %0, %1, %2" : "=v"(c6w) : "v"(e[12]), "v"(e[13]));
        asm("v_cvt_pk_bf16_f32 %0, %1, %2" : "=v"(c7w) : "v"(e[14]), "v"(e[15]));
        asm("v_permlane32_swap_b32 %0, %1" : "+v"(c0w), "+v"(c2w));
        asm("v_permlane32_swap_b32 %0, %1" : "+v"(c1w), "+v"(c3w));
        asm("v_permlane32_swap_b32 %0, %1" : "+v"(c4w), "+v"(c6w));
        asm("v_permlane32_swap_b32 %0, %1" : "+v"(c5w), "+v"(c7w));
        const uint4 b0u = make_uint4(c0w, c1w, c2w, c3w);
        const uint4 b1u = make_uint4(c4w, c5w, c6w, c7w);
        acc = __builtin_amdgcn_mfma_f32_32x32x16_bf16(v0, __builtin_bit_cast(bf16x8, b0u), acc, 0, 0, 0);
        acc = __builtin_amdgcn_mfma_f32_32x32x16_bf16(v1, __builtin_bit_cast(bf16x8, b1u), acc, 0, 0, 0);
    }

    // ---- cross-wave flash merge (8 key-split partials) ----
    __shared__ float o_lds[8][32][33];
    __shared__ float m_l[8][32];
    __shared__ float l_l[8][32];
    if (hi == 0) { m_l[w][lq] = m_run; l_l[w][lq] = l_run; }
    #pragma unroll
    for (int r = 0; r < 16; ++r) {
        const int d = (r & 3) + 8 * (r >> 2) + 4 * hi;
        o_lds[w][d][lq] = acc[r];
    }
    __syncthreads();
    {
        const int q = t >> 4;        // 0..31
        const int dp = t & 15;       // float2 over d
        float M = m_l[0][q];
        #pragma unroll
        for (int w2 = 1; w2 < 8; ++w2) M = fmaxf(M, m_l[w2][q]);
        float L = 0.f, fac[8];
        #pragma unroll
        for (int w2 = 0; w2 < 8; ++w2) {
            fac[w2] = __builtin_amdgcn_exp2f(m_l[w2][q] - M);
            L += l_l[w2][q] * fac[w2];
        }
        const float invL = 1.f / L;
        float o0 = 0.f, o1 = 0.f;
        #pragma unroll
        for (int w2 = 0; w2 < 8; ++w2) {
            o0 += o_lds[w2][dp * 2][q] * fac[w2];
            o1 += o_lds[w2][dp * 2 + 1][q] * fac[w2];
        }
        o0 = fmaxf(o0 * invL, 0.f);
        o1 = fmaxf(o1 * invL, 0.f);
        float2 ov = make_float2(o0, o1);
        *reinterpret_cast<float2*>(out + ((size_t)(b * N_ + q0 + q) * H_ + h) * D_ + dp * 2) = ov;
    }
}

extern "C" void kernel_launch(void* const* d_in, const int* in_sizes, int n_in,
                              void* d_out, int out_size, void* d_ws, size_t ws_size,
                              hipStream_t stream) {
    // inputs: vt, x, adj, fc_w, fc_b, Q1, Q2, K, V (all fp32)
    const float* x    = (const float*)d_in[1];
    const float* adj  = (const float*)d_in[2];
    const float* fc_w = (const float*)d_in[3];
    const float* fc_b = (const float*)d_in[4];
    const float* Q1   = (const float*)d_in[5];
    const float* Q2   = (const float*)d_in[6];
    const float* K    = (const float*)d_in[7];
    const float* V    = (const float*)d_in[8];
    float* out = (float*)d_out;

    char* ws = (char*)d_ws;
    const size_t MB = 1024 * 1024;
    unsigned short* QtH = (unsigned short*)(ws);             // 2 MB each
    unsigned short* QtL = (unsigned short*)(ws + 2 * MB);
    unsigned short* KtH = (unsigned short*)(ws + 4 * MB);
    unsigned short* KtL = (unsigned short*)(ws + 6 * MB);
    unsigned short* Vt  = (unsigned short*)(ws + 8 * MB);
    unsigned short* VtT = (unsigned short*)(ws + 10 * MB);
    unsigned*     maskT = (unsigned*)    (ws + 12 * MB);     // 2 MB

    hipLaunchKernelGGL(fused_proj_pack, dim3(1024 + 4096), dim3(128), 0, stream,
                       x, fc_w, fc_b, Q1, Q2, K, V, adj,
                       QtH, QtL, KtH, KtL, Vt, maskT);
    hipLaunchKernelGGL(vtrans, dim3(8 * (N_ / 64)), dim3(256), 0, stream, Vt, VtT);
    hipLaunchKernelGGL(flash_mfma, dim3(B_ * H_ * (N_ / 32)), dim3(512), 0, stream,
                       QtH, QtL, KtH, KtL, VtT, maskT, out);
}